// Round 3
// baseline (241.661 us; speedup 1.0000x reference)
//
#include <hip/hip_runtime.h>

typedef unsigned short u16;
typedef unsigned int u32;
typedef __attribute__((ext_vector_type(8))) short short8;
typedef __attribute__((ext_vector_type(4))) float f32x4;

__device__ __forceinline__ u16 f2bf(float f) {
    union { float f; u32 u; } c; c.f = f;
    u32 u = c.u;
    return (u16)((u + 0x7fffu + ((u >> 16) & 1u)) >> 16);
}

#define MFMA16(A, B, C) __builtin_amdgcn_mfma_f32_16x16x32_bf16((A), (B), (C), 0, 0, 0)

// ---------------------------------------------------------------------------
// Unified prepass.
//   XF  [bt*64+m2][bl][ks][lane=q*16+lr][8] : x[bt*64+bl*16+lr][m2*64+ks*32+q*8+j]
//   W1F [m2][nb][ct][ks][lane][8]           : W1[m2][m1=ks*32+q*8+j][c=nb*32+ct*16+lr]
//   W2F [n1][m2b][nt][lane][8]              : W2[n1][k=m2b*32+q*8+j][n2=nt*16+lr]
// XF path is LDS-free: one XF 16-B fragment == 8 consecutive x floats of one
// row, so each wave reads one row x 2 KB CONTIGUOUS fp32 (lane l -> floats
// l*8..l*8+7 across 8 m2-tiles), converts in-register, stores one short8.
// The 16-B stores at 256-B stride write-combine in L2 (each 256-B region is
// completed by the block within its 16 row-iterations).
// Grid: 512 XF blocks (bt x 8-tile col group) + 64 W1F + 64 W2F, 256 thr.
// ---------------------------------------------------------------------------
__global__ __launch_bounds__(256) void prep(const float* __restrict__ x,
                                            const float* __restrict__ W1,
                                            const float* __restrict__ W2,
                                            u16* __restrict__ XF,
                                            u16* __restrict__ W1F,
                                            u16* __restrict__ W2F) {
    __shared__ u16 sh[16384];
    const int bid = blockIdx.x;
    const int t = threadIdx.x;

    if (bid < 512) {
        // ---- XF: (bt, m2g) -> rows bt*64..+63, cols m2g*512..+511 ----
        const int bt = bid >> 3, m2g = bid & 7;
        const int w = t >> 6, l = t & 63;
        const int m2i = l >> 3;            // which of the 8 m2-tiles
        const int ks = (l >> 2) & 1;
        const int q = l & 3;
        const float* base = x + ((size_t)bt * 64) * 4096 + m2g * 512 + l * 8;
        u16* tilebase = XF + ((size_t)(bt * 64 + m2g * 8 + m2i)) * 4096;
        #pragma unroll
        for (int rr = 0; rr < 16; ++rr) {
            const int row = rr * 4 + w;
            const float* p = base + (size_t)row * 4096;
            float4 f0 = *(const float4*)(p);
            float4 f1 = *(const float4*)(p + 4);
            short8 r;
            r[0] = (short)f2bf(f0.x); r[1] = (short)f2bf(f0.y);
            r[2] = (short)f2bf(f0.z); r[3] = (short)f2bf(f0.w);
            r[4] = (short)f2bf(f1.x); r[5] = (short)f2bf(f1.y);
            r[6] = (short)f2bf(f1.z); r[7] = (short)f2bf(f1.w);
            const int bl = row >> 4, lr = row & 15;
            *(short8*)(tilebase + (((bl * 2 + ks) * 4 + q) << 7) + lr * 8) = r;
        }
    } else if (bid < 576) {
        // ---- W1F: one m2 slice (64 x 256 fp32 -> 32 KB bf16) ----
        const int m2 = bid - 512;
        const float4* src = (const float4*)(W1 + (size_t)m2 * 16384);
        #pragma unroll
        for (int s = 0; s < 16; ++s) {
            float4 f = src[s * 256 + t];
            float fv[4] = {f.x, f.y, f.z, f.w};
            #pragma unroll
            for (int e = 0; e < 4; ++e) {
                int elem = (s * 256 + t) * 4 + e;
                int m1 = elem >> 8, c = elem & 255;
                int nb = c >> 5, ct = (c >> 4) & 1, lr = c & 15;
                int ks = m1 >> 5, q = (m1 >> 3) & 3, j = m1 & 7;
                sh[(((((nb * 2 + ct) * 2 + ks) * 4 + q)) << 7) + lr * 8 + j] =
                    f2bf(fv[e]);
            }
        }
        __syncthreads();
        u16* dst = W1F + (size_t)m2 * 16384 + t * 64;
        #pragma unroll
        for (int s = 0; s < 8; ++s)
            *(short8*)(dst + s * 8) = *(const short8*)(&sh[t * 64 + s * 8]);
    } else {
        // ---- W2F: one n1 slice (256 x 64 fp32 -> 32 KB bf16) ----
        const int n1 = bid - 576;
        const float4* src = (const float4*)(W2 + (size_t)n1 * 16384);
        #pragma unroll
        for (int s = 0; s < 16; ++s) {
            float4 f = src[s * 256 + t];
            float fv[4] = {f.x, f.y, f.z, f.w};
            #pragma unroll
            for (int e = 0; e < 4; ++e) {
                int elem = (s * 256 + t) * 4 + e;
                int k = elem >> 6, n2 = elem & 63;
                int m2b = k >> 5, q = (k >> 3) & 3, j = k & 7;
                int nt = n2 >> 4, lr = n2 & 15;
                sh[((((m2b * 4 + nt) * 4 + q)) << 7) + lr * 8 + j] = f2bf(fv[e]);
            }
        }
        __syncthreads();
        u16* dst = W2F + (size_t)n1 * 16384 + t * 64;
        #pragma unroll
        for (int s = 0; s < 8; ++s)
            *(short8*)(dst + s * 8) = *(const short8*)(&sh[t * 64 + s * 8]);
    }
}

// ---------------------------------------------------------------------------
// btt_p: round-0 proven dataflow (XF/W1F/W2F fragment-major bf16, 64-row
// tiles, grid 512 = 64 bt x 8 nb, t through LDS) with the barrier drain
// removed (the documented m97-ceiling stall):
//  * t_lds double-buffered -> ONE barrier per m2b iteration.
//  * raw s_barrier + lgkmcnt(0)-only wait (no vmcnt drain), fenced with
//    sched_barrier(0) per guide rule #18.
//  * next iteration's XF fragments register-prefetched BEFORE the barrier ->
//    the HBM stream stays in flight across it (T4 counted-wait principle).
// Hazards: RAW t (write -> lgkm0 -> barrier -> read); WAR t (reads of iter i
// complete at iter i+1's lgkmcnt(0); same-buffer writes only after barrier
// i+1). Math core / fragment addressing byte-identical to round-0 btt_main.
// ---------------------------------------------------------------------------
__global__ __launch_bounds__(512, 4) void btt_p(const u16* __restrict__ XF,
                                                const u16* __restrict__ W1F,
                                                const u16* __restrict__ W2F,
                                                float* __restrict__ out) {
    __shared__ u16 t_lds[2][64 * 260];

    const int tid = threadIdx.x;
    const int w = tid >> 6;       // wave 0..7
    const int lane = tid & 63;
    const int q = lane >> 4;      // quad
    const int lr = lane & 15;
    const int bt = blockIdx.x & 63;
    const int nb = blockIdx.x >> 6;
    const int n1 = nb * 8 + w;

    const f32x4 fz = {0.f, 0.f, 0.f, 0.f};
    f32x4 acc2[4][4];             // y[b(4x16)][n2(4x16)]
    #pragma unroll
    for (int i = 0; i < 4; ++i)
        #pragma unroll
        for (int j = 0; j < 4; ++j) acc2[i][j] = fz;

    // xbase points at tile (bt*64 + m2) for m2 = w; +8*4096 per m2b step.
    const u16* xbase = XF + ((size_t)bt * 64 + w) * 4096 + lane * 8;

    // prologue: prefetch XF fragments for m2b = 0
    short8 b1c[4][2];
    #pragma unroll
    for (int bl = 0; bl < 4; ++bl)
        #pragma unroll
        for (int ks = 0; ks < 2; ++ks)
            b1c[bl][ks] = *(const short8*)(xbase + (bl * 2 + ks) * 512);

    for (int m2b = 0; m2b < 8; ++m2b) {
        const int m2 = m2b * 8 + w;
        const int p = m2b & 1;

        // ---- this iter's W1 fragments (L2-resident) ----
        short8 a1[2][2];
        {
            const u16* pw = W1F + ((size_t)m2 * 8 + nb) * 2048 + lane * 8;
            #pragma unroll
            for (int ct = 0; ct < 2; ++ct)
                #pragma unroll
                for (int ks = 0; ks < 2; ++ks)
                    a1[ct][ks] = *(const short8*)(pw + (ct * 2 + ks) * 512);
        }
        // ---- prefetch NEXT iter's XF fragments (in flight across barrier;
        //      wraps to tile 0 on last iter, result unused) ----
        short8 b1n[4][2];
        {
            const u16* xn = xbase + (size_t)(((m2b + 1) & 7) * 8) * 4096;
            #pragma unroll
            for (int bl = 0; bl < 4; ++bl)
                #pragma unroll
                for (int ks = 0; ks < 2; ++ks)
                    b1n[bl][ks] = *(const short8*)(xn + (bl * 2 + ks) * 512);
        }

        // ---- stage 1: tT[c'(32)][b(64)] = W1_slice(32x64) . xT(64x64) ----
        f32x4 acc1[2][4];
        #pragma unroll
        for (int ct = 0; ct < 2; ++ct)
            #pragma unroll
            for (int bl = 0; bl < 4; ++bl) acc1[ct][bl] = fz;
        #pragma unroll
        for (int ks = 0; ks < 2; ++ks)
            #pragma unroll
            for (int ct = 0; ct < 2; ++ct)
                #pragma unroll
                for (int bl = 0; bl < 4; ++bl)
                    acc1[ct][bl] = MFMA16(a1[ct][ks], b1c[bl][ks], acc1[ct][bl]);

        // tT -> t_lds[p][b][w*32+c']; D: row=c'=ct*16+q*4+g, col=b=bl*16+lr
        #pragma unroll
        for (int ct = 0; ct < 2; ++ct)
            #pragma unroll
            for (int bl = 0; bl < 4; ++bl) {
                int off = (bl * 16 + lr) * 260 + w * 32 + ct * 16 + q * 4;
                u32 lo = (u32)f2bf(acc1[ct][bl][0]) | ((u32)f2bf(acc1[ct][bl][1]) << 16);
                u32 hi = (u32)f2bf(acc1[ct][bl][2]) | ((u32)f2bf(acc1[ct][bl][3]) << 16);
                *(uint2*)(&t_lds[p][off]) = make_uint2(lo, hi);
            }

        // ---- sync: LDS-only wait + raw barrier (NO vmcnt drain) ----
        __builtin_amdgcn_sched_barrier(0);
        asm volatile("s_waitcnt lgkmcnt(0)" ::: "memory");
        __builtin_amdgcn_sched_barrier(0);
        __builtin_amdgcn_s_barrier();
        __builtin_amdgcn_sched_barrier(0);

        // ---- stage 2: y[b][n2] += t2(64x32) . W2_slice(32x64) ----
        short8 a2[4];
        #pragma unroll
        for (int bl = 0; bl < 4; ++bl) {
            int base = (bl * 16 + lr) * 260 + (2 * q) * 32 + w * 4;
            union { short8 v; uint2 u[2]; } tmp;
            tmp.u[0] = *(const uint2*)(&t_lds[p][base]);
            tmp.u[1] = *(const uint2*)(&t_lds[p][base + 32]);
            a2[bl] = tmp.v;
        }
        short8 b2[4];
        {
            const u16* pw = W2F + (size_t)n1 * 16384 + m2b * 2048 + lane * 8;
            #pragma unroll
            for (int nt = 0; nt < 4; ++nt)
                b2[nt] = *(const short8*)(pw + nt * 512);
        }
        #pragma unroll
        for (int bl = 0; bl < 4; ++bl)
            #pragma unroll
            for (int nt = 0; nt < 4; ++nt)
                acc2[bl][nt] = MFMA16(a2[bl], b2[nt], acc2[bl][nt]);

        // rotate prefetch buffer
        #pragma unroll
        for (int bl = 0; bl < 4; ++bl)
            #pragma unroll
            for (int ks = 0; ks < 2; ++ks)
                b1c[bl][ks] = b1n[bl][ks];
    }

    // ---- epilogue: D rows = b (q*4+g), cols = n2 (lr); fp32 stores ----
    #pragma unroll
    for (int bl = 0; bl < 4; ++bl)
        #pragma unroll
        for (int nt = 0; nt < 4; ++nt)
            #pragma unroll
            for (int g = 0; g < 4; ++g) {
                long row = bt * 64 + bl * 16 + q * 4 + g;
                long col = (long)n1 * 64 + nt * 16 + lr;
                out[row * 4096 + col] = acc2[bl][nt][g];
            }
}

// ---------------------------------------------------------------------------
// Fallback (ws too small): HW-proven scalar-weight-load kernel.
// ---------------------------------------------------------------------------
__global__ __launch_bounds__(512) void btt_nows(const float* __restrict__ x,
                                                const float* __restrict__ W1,
                                                const float* __restrict__ W2,
                                                float* __restrict__ out) {
    __shared__ u16 t_lds[64 * 260];
    const int tid = threadIdx.x;
    const int w = tid >> 6;
    const int lane = tid & 63;
    const int q = lane >> 4;
    const int lr = lane & 15;
    const int bt = blockIdx.x & 63;
    const int nb = blockIdx.x >> 6;
    const int n1 = nb * 8 + w;

    const f32x4 fz = {0.f, 0.f, 0.f, 0.f};
    f32x4 acc2[4][4];
    #pragma unroll
    for (int i = 0; i < 4; ++i)
        #pragma unroll
        for (int j = 0; j < 4; ++j) acc2[i][j] = fz;

    for (int m2b = 0; m2b < 8; ++m2b) {
        const int m2 = m2b * 8 + w;
        short8 ax[4][2];
        #pragma unroll
        for (int bl = 0; bl < 4; ++bl)
            #pragma unroll
            for (int ks = 0; ks < 2; ++ks) {
                const float* p = x + (size_t)(bt * 64 + bl * 16 + lr) * 4096 +
                                 m2 * 64 + ks * 32 + q * 8;
                float4 ua = *(const float4*)(p);
                float4 ub = *(const float4*)(p + 4);
                short8 r;
                r[0] = (short)f2bf(ua.x); r[1] = (short)f2bf(ua.y);
                r[2] = (short)f2bf(ua.z); r[3] = (short)f2bf(ua.w);
                r[4] = (short)f2bf(ub.x); r[5] = (short)f2bf(ub.y);
                r[6] = (short)f2bf(ub.z); r[7] = (short)f2bf(ub.w);
                ax[bl][ks] = r;
            }
        short8 bw1[2][2];
        #pragma unroll
        for (int ct = 0; ct < 2; ++ct)
            #pragma unroll
            for (int ks = 0; ks < 2; ++ks)
                #pragma unroll
                for (int j = 0; j < 8; ++j)
                    bw1[ct][ks][j] = (short)f2bf(W1[m2 * 16384 +
                                                    (ks * 32 + q * 8 + j) * 256 +
                                                    nb * 32 + ct * 16 + lr]);
        f32x4 acc1[4][2];
        #pragma unroll
        for (int bl = 0; bl < 4; ++bl)
            #pragma unroll
            for (int ct = 0; ct < 2; ++ct) acc1[bl][ct] = fz;
        #pragma unroll
        for (int ks = 0; ks < 2; ++ks)
            #pragma unroll
            for (int bl = 0; bl < 4; ++bl)
                #pragma unroll
                for (int ct = 0; ct < 2; ++ct)
                    acc1[bl][ct] = MFMA16(ax[bl][ks], bw1[ct][ks], acc1[bl][ct]);

        __syncthreads();
        #pragma unroll
        for (int bl = 0; bl < 4; ++bl)
            #pragma unroll
            for (int ct = 0; ct < 2; ++ct)
                #pragma unroll
                for (int g = 0; g < 4; ++g)
                    t_lds[(bl * 16 + q * 4 + g) * 260 + w * 32 + ct * 16 + lr] =
                        f2bf(acc1[bl][ct][g]);
        __syncthreads();

        short8 a2[4];
        #pragma unroll
        for (int bl = 0; bl < 4; ++bl) {
            int base = (bl * 16 + lr) * 260 + (2 * q) * 32 + w * 4;
            union { short8 v; uint2 u[2]; } tmp;
            tmp.u[0] = *(const uint2*)(&t_lds[base]);
            tmp.u[1] = *(const uint2*)(&t_lds[base + 32]);
            a2[bl] = tmp.v;
        }
        short8 b2[4];
        #pragma unroll
        for (int nt = 0; nt < 4; ++nt)
            #pragma unroll
            for (int j = 0; j < 8; ++j)
                b2[nt][j] = (short)f2bf(W2[n1 * 16384 +
                                           (m2b * 32 + q * 8 + j) * 64 +
                                           nt * 16 + lr]);
        #pragma unroll
        for (int bl = 0; bl < 4; ++bl)
            #pragma unroll
            for (int nt = 0; nt < 4; ++nt)
                acc2[bl][nt] = MFMA16(a2[bl], b2[nt], acc2[bl][nt]);
    }

    #pragma unroll
    for (int bl = 0; bl < 4; ++bl)
        #pragma unroll
        for (int nt = 0; nt < 4; ++nt)
            #pragma unroll
            for (int g = 0; g < 4; ++g) {
                long row = bt * 64 + bl * 16 + q * 4 + g;
                long col = (long)n1 * 64 + nt * 16 + lr;
                out[row * 4096 + col] = acc2[bl][nt][g];
            }
}

extern "C" void kernel_launch(void* const* d_in, const int* in_sizes, int n_in,
                              void* d_out, int out_size, void* d_ws, size_t ws_size,
                              hipStream_t stream) {
    const float* x  = (const float*)d_in[0];   // (4096, 4096) fp32
    const float* W1 = (const float*)d_in[1];   // (64, 64, 256) fp32
    const float* W2 = (const float*)d_in[2];   // (64, 256, 64) fp32
    float* out = (float*)d_out;

    const size_t N_W1F = (size_t)64 * 16384;          // 2 MiB
    const size_t N_W2F = (size_t)64 * 16384;          // 2 MiB
    const size_t N_XF  = (size_t)4096 * 4096;         // 32 MiB
    const size_t WS_NEED = (N_W1F + N_W2F + N_XF) * sizeof(u16);  // 36 MiB

    if (ws_size >= WS_NEED) {
        u16* W1F = (u16*)d_ws;
        u16* W2F = W1F + N_W1F;
        u16* XF  = W2F + N_W2F;
        prep<<<512 + 64 + 64, 256, 0, stream>>>(x, W1, W2, XF, W1F, W2F);
        btt_p<<<512, 512, 0, stream>>>(XF, W1F, W2F, out);
    } else {
        btt_nows<<<512, 512, 0, stream>>>(x, W1, W2, out);
    }
}

// Round 4
// 164.341 us; speedup vs baseline: 1.4705x; 1.4705x over previous
//
#include <hip/hip_runtime.h>

typedef unsigned short u16;
typedef unsigned int u32;
typedef __attribute__((ext_vector_type(8))) short short8;
typedef __attribute__((ext_vector_type(4))) float f32x4;

__device__ __forceinline__ u16 f2bf(float f) {
    union { float f; u32 u; } c; c.f = f;
    u32 u = c.u;
    return (u16)((u + 0x7fffu + ((u >> 16) & 1u)) >> 16);
}

#define MFMA16(A, B, C) __builtin_amdgcn_mfma_f32_16x16x32_bf16((A), (B), (C), 0, 0, 0)

// ---------------------------------------------------------------------------
// Unified prepass (round-0 proven version, restored verbatim: LDS-staged,
// fully-coalesced contiguous stores — measured ~29 us; the round-3 "LDS-free"
// scattered-store variant was ~37 us, reverted).
//   XF  [bt][m2][bl][ks][lane][8] : x[bt*64+bl*16+lr][m2*64+ks*32+q*8+j]
//   W1F [m2][nb][ct][ks][lane][8] : W1[m2][m1=ks*32+q*8+j][c=nb*32+ct*16+lr]
//   W2F [n1][m2b][nt][lane][8]    : W2[n1][k=m2b*32+q*8+j][n2=nt*16+lr]
// (lane = q*16+lr).  Grid: 4096 XF blocks + 64 W1F + 64 W2F, 256 thr.
// ---------------------------------------------------------------------------
__global__ __launch_bounds__(256) void prep_all(const float* __restrict__ x,
                                                const float* __restrict__ W1,
                                                const float* __restrict__ W2,
                                                u16* __restrict__ W1F,
                                                u16* __restrict__ W2F,
                                                u16* __restrict__ XF) {
    __shared__ u16 sh[16384];
    const int bid = blockIdx.x;
    const int t = threadIdx.x;

    if (bid < 4096) {
        // ---- XF: tile (bt, m2) = 64 rows x 64 cols, 8 KB out ----
        const int bt = bid >> 6, m2 = bid & 63;
        const int r = t >> 2, lr = r & 15, bl = r >> 4;
        const int c0 = (t & 3) * 16;
        const float* src = x + ((size_t)bt * 64 + r) * 4096 + m2 * 64 + c0;
        float4 f[4];
        #pragma unroll
        for (int s = 0; s < 4; ++s) f[s] = ((const float4*)src)[s];
        u16 v[16];
        #pragma unroll
        for (int s = 0; s < 4; ++s) {
            v[s * 4 + 0] = f2bf(f[s].x); v[s * 4 + 1] = f2bf(f[s].y);
            v[s * 4 + 2] = f2bf(f[s].z); v[s * 4 + 3] = f2bf(f[s].w);
        }
        #pragma unroll
        for (int h = 0; h < 2; ++h) {
            int cc = (t & 3) * 2 + h;          // chunk of 8 cols
            int ks = cc >> 2, q = cc & 3;
            int off = (((bl * 2 + ks) * 4 + q) << 7) + lr * 8;
            short8 pk;
            #pragma unroll
            for (int j = 0; j < 8; ++j) pk[j] = (short)v[h * 8 + j];
            *(short8*)(&sh[off]) = pk;
        }
        __syncthreads();
        u16* dst = XF + (size_t)bid * 4096 + t * 16;
        *(short8*)(dst) = *(const short8*)(&sh[t * 16]);
        *(short8*)(dst + 8) = *(const short8*)(&sh[t * 16 + 8]);
    } else if (bid < 4160) {
        // ---- W1F: one m2 slice (64 x 256 fp32 -> 32 KB bf16) ----
        const int m2 = bid - 4096;
        const float* src = W1 + (size_t)m2 * 16384 + t * 64;
        #pragma unroll
        for (int s = 0; s < 16; ++s) {
            float4 f = ((const float4*)src)[s];
            float fv[4] = {f.x, f.y, f.z, f.w};
            #pragma unroll
            for (int e = 0; e < 4; ++e) {
                int elem = t * 64 + s * 4 + e;
                int m1 = elem >> 8, c = elem & 255;
                int nb = c >> 5, ct = (c >> 4) & 1, lr = c & 15;
                int ks = m1 >> 5, q = (m1 >> 3) & 3, j = m1 & 7;
                sh[(((((nb * 2 + ct) * 2 + ks) * 4 + q)) << 7) + lr * 8 + j] =
                    f2bf(fv[e]);
            }
        }
        __syncthreads();
        u16* dst = W1F + (size_t)m2 * 16384 + t * 64;
        #pragma unroll
        for (int s = 0; s < 8; ++s)
            *(short8*)(dst + s * 8) = *(const short8*)(&sh[t * 64 + s * 8]);
    } else {
        // ---- W2F: one n1 slice (256 x 64 fp32 -> 32 KB bf16) ----
        const int n1 = bid - 4160;
        const float* src = W2 + (size_t)n1 * 16384 + t * 64;
        #pragma unroll
        for (int s = 0; s < 16; ++s) {
            float4 f = ((const float4*)src)[s];
            float fv[4] = {f.x, f.y, f.z, f.w};
            #pragma unroll
            for (int e = 0; e < 4; ++e) {
                int elem = t * 64 + s * 4 + e;
                int k = elem >> 6, n2 = elem & 63;
                int m2b = k >> 5, q = (k >> 3) & 3, j = k & 7;
                int nt = n2 >> 4, lr = n2 & 15;
                sh[((((m2b * 4 + nt) * 4 + q)) << 7) + lr * 8 + j] = f2bf(fv[e]);
            }
        }
        __syncthreads();
        u16* dst = W2F + (size_t)n1 * 16384 + t * 64;
        #pragma unroll
        for (int s = 0; s < 8; ++s)
            *(short8*)(dst + s * 8) = *(const short8*)(&sh[t * 64 + s * 8]);
    }
}

// ---------------------------------------------------------------------------
// btt_db: round-0 HW-proven btt_main (48.4 us, VGPR 80, FETCH 49 MB) with the
// ONLY register-safe pipeline change, cleanly isolated:
//  * t_lds double-buffered -> ONE __syncthreads per m2b iter (was 2).
//    WAR safety: reads(i, buf p) precede barrier(i+1) in every wave's program
//    order (enforced by __syncthreads' lgkm drain); writes(i+2, buf p) follow
//    barrier(i+1). RAW: write -> barrier -> read, standard.
//  * b2 load hoisted to iteration top (+16 VGPR, in flight across stage-1 +
//    barrier instead of being issued on the post-barrier critical path).
//  * NO cross-iteration prefetch, NO launch_bounds min-waves clamp, plain
//    __syncthreads — round 3 proved that combo spills (VGPR 64, 310 MB
//    scratch writes). Expect VGPR ~96 <= 128: occupancy unchanged.
// Math core / fragment addressing byte-identical to round-0 btt_main
// (m89/m91-verified MFMA mappings, t_lds stride 260, XCD-friendly bt/nb map).
// ---------------------------------------------------------------------------
__global__ __launch_bounds__(512) void btt_db(const u16* __restrict__ XF,
                                              const u16* __restrict__ W1F,
                                              const u16* __restrict__ W2F,
                                              float* __restrict__ out) {
    __shared__ u16 t_lds[2][64 * 260];   // 2 x 33.3 KB (66,560 B: allocatable,
                                         // proven in round 3)

    const int tid = threadIdx.x;
    const int w = tid >> 6;       // wave 0..7
    const int lane = tid & 63;
    const int q = lane >> 4;      // quad
    const int lr = lane & 15;
    const int bt = blockIdx.x & 63;
    const int nb = blockIdx.x >> 6;
    const int n1 = nb * 8 + w;

    const f32x4 fz = {0.f, 0.f, 0.f, 0.f};
    f32x4 acc2[4][4];             // y[b(4x16)][n2(4x16)]
    #pragma unroll
    for (int i = 0; i < 4; ++i)
        #pragma unroll
        for (int j = 0; j < 4; ++j) acc2[i][j] = fz;

    for (int m2b = 0; m2b < 8; ++m2b) {
        const int m2 = m2b * 8 + w;
        const int p = m2b & 1;

        // ---- all of this iteration's global loads, issued up front ----
        short8 a1[2][2];
        {
            const u16* pw = W1F + ((size_t)m2 * 8 + nb) * 2048 + lane * 8;
            #pragma unroll
            for (int ct = 0; ct < 2; ++ct)
                #pragma unroll
                for (int ks = 0; ks < 2; ++ks)
                    a1[ct][ks] = *(const short8*)(pw + (ct * 2 + ks) * 512);
        }
        short8 b2[4];
        {
            const u16* pw = W2F + (size_t)n1 * 16384 + m2b * 2048 + lane * 8;
            #pragma unroll
            for (int nt = 0; nt < 4; ++nt)
                b2[nt] = *(const short8*)(pw + nt * 512);
        }
        short8 b1[4][2];
        {
            const u16* px = XF + ((size_t)bt * 64 + m2) * 4096 + lane * 8;
            #pragma unroll
            for (int bl = 0; bl < 4; ++bl)
                #pragma unroll
                for (int ks = 0; ks < 2; ++ks)
                    b1[bl][ks] = *(const short8*)(px + (bl * 2 + ks) * 512);
        }

        // ---- stage 1: tT[c'(32)][b(64)] = W1_slice(32x64) . xT(64x64) ----
        f32x4 acc1[2][4];
        #pragma unroll
        for (int ct = 0; ct < 2; ++ct)
            #pragma unroll
            for (int bl = 0; bl < 4; ++bl) acc1[ct][bl] = fz;
        #pragma unroll
        for (int ks = 0; ks < 2; ++ks)
            #pragma unroll
            for (int ct = 0; ct < 2; ++ct)
                #pragma unroll
                for (int bl = 0; bl < 4; ++bl)
                    acc1[ct][bl] = MFMA16(a1[ct][ks], b1[bl][ks], acc1[ct][bl]);

        // tT -> t_lds[p][b][w*32+c']; D: row=c'=ct*16+q*4+g, col=b=bl*16+lr
        #pragma unroll
        for (int ct = 0; ct < 2; ++ct)
            #pragma unroll
            for (int bl = 0; bl < 4; ++bl) {
                int off = (bl * 16 + lr) * 260 + w * 32 + ct * 16 + q * 4;
                u32 lo = (u32)f2bf(acc1[ct][bl][0]) | ((u32)f2bf(acc1[ct][bl][1]) << 16);
                u32 hi = (u32)f2bf(acc1[ct][bl][2]) | ((u32)f2bf(acc1[ct][bl][3]) << 16);
                *(uint2*)(&t_lds[p][off]) = make_uint2(lo, hi);
            }

        __syncthreads();   // single barrier per iteration

        // ---- stage 2: y[b][n2] += t2(64x32) . W2_slice(32x64) ----
        short8 a2[4];
        #pragma unroll
        for (int bl = 0; bl < 4; ++bl) {
            int base = (bl * 16 + lr) * 260 + (2 * q) * 32 + w * 4;
            union { short8 v; uint2 u[2]; } tmp;
            tmp.u[0] = *(const uint2*)(&t_lds[p][base]);
            tmp.u[1] = *(const uint2*)(&t_lds[p][base + 32]);
            a2[bl] = tmp.v;
        }
        #pragma unroll
        for (int bl = 0; bl < 4; ++bl)
            #pragma unroll
            for (int nt = 0; nt < 4; ++nt)
                acc2[bl][nt] = MFMA16(a2[bl], b2[nt], acc2[bl][nt]);
    }

    // ---- epilogue: D rows = b (q*4+g), cols = n2 (lr); fp32 stores ----
    #pragma unroll
    for (int bl = 0; bl < 4; ++bl)
        #pragma unroll
        for (int nt = 0; nt < 4; ++nt)
            #pragma unroll
            for (int g = 0; g < 4; ++g) {
                long row = bt * 64 + bl * 16 + q * 4 + g;
                long col = (long)n1 * 64 + nt * 16 + lr;
                out[row * 4096 + col] = acc2[bl][nt][g];
            }
}

// ---------------------------------------------------------------------------
// Fallback (ws too small): HW-proven scalar-weight-load kernel.
// ---------------------------------------------------------------------------
__global__ __launch_bounds__(512) void btt_nows(const float* __restrict__ x,
                                                const float* __restrict__ W1,
                                                const float* __restrict__ W2,
                                                float* __restrict__ out) {
    __shared__ u16 t_lds[64 * 260];
    const int tid = threadIdx.x;
    const int w = tid >> 6;
    const int lane = tid & 63;
    const int q = lane >> 4;
    const int lr = lane & 15;
    const int bt = blockIdx.x & 63;
    const int nb = blockIdx.x >> 6;
    const int n1 = nb * 8 + w;

    const f32x4 fz = {0.f, 0.f, 0.f, 0.f};
    f32x4 acc2[4][4];
    #pragma unroll
    for (int i = 0; i < 4; ++i)
        #pragma unroll
        for (int j = 0; j < 4; ++j) acc2[i][j] = fz;

    for (int m2b = 0; m2b < 8; ++m2b) {
        const int m2 = m2b * 8 + w;
        short8 ax[4][2];
        #pragma unroll
        for (int bl = 0; bl < 4; ++bl)
            #pragma unroll
            for (int ks = 0; ks < 2; ++ks) {
                const float* p = x + (size_t)(bt * 64 + bl * 16 + lr) * 4096 +
                                 m2 * 64 + ks * 32 + q * 8;
                float4 ua = *(const float4*)(p);
                float4 ub = *(const float4*)(p + 4);
                short8 r;
                r[0] = (short)f2bf(ua.x); r[1] = (short)f2bf(ua.y);
                r[2] = (short)f2bf(ua.z); r[3] = (short)f2bf(ua.w);
                r[4] = (short)f2bf(ub.x); r[5] = (short)f2bf(ub.y);
                r[6] = (short)f2bf(ub.z); r[7] = (short)f2bf(ub.w);
                ax[bl][ks] = r;
            }
        short8 bw1[2][2];
        #pragma unroll
        for (int ct = 0; ct < 2; ++ct)
            #pragma unroll
            for (int ks = 0; ks < 2; ++ks)
                #pragma unroll
                for (int j = 0; j < 8; ++j)
                    bw1[ct][ks][j] = (short)f2bf(W1[m2 * 16384 +
                                                    (ks * 32 + q * 8 + j) * 256 +
                                                    nb * 32 + ct * 16 + lr]);
        f32x4 acc1[4][2];
        #pragma unroll
        for (int bl = 0; bl < 4; ++bl)
            #pragma unroll
            for (int ct = 0; ct < 2; ++ct) acc1[bl][ct] = fz;
        #pragma unroll
        for (int ks = 0; ks < 2; ++ks)
            #pragma unroll
            for (int bl = 0; bl < 4; ++bl)
                #pragma unroll
                for (int ct = 0; ct < 2; ++ct)
                    acc1[bl][ct] = MFMA16(ax[bl][ks], bw1[ct][ks], acc1[bl][ct]);

        __syncthreads();
        #pragma unroll
        for (int bl = 0; bl < 4; ++bl)
            #pragma unroll
            for (int ct = 0; ct < 2; ++ct)
                #pragma unroll
                for (int g = 0; g < 4; ++g)
                    t_lds[(bl * 16 + q * 4 + g) * 260 + w * 32 + ct * 16 + lr] =
                        f2bf(acc1[bl][ct][g]);
        __syncthreads();

        short8 a2[4];
        #pragma unroll
        for (int bl = 0; bl < 4; ++bl) {
            int base = (bl * 16 + lr) * 260 + (2 * q) * 32 + w * 4;
            union { short8 v; uint2 u[2]; } tmp;
            tmp.u[0] = *(const uint2*)(&t_lds[base]);
            tmp.u[1] = *(const uint2*)(&t_lds[base + 32]);
            a2[bl] = tmp.v;
        }
        short8 b2[4];
        #pragma unroll
        for (int nt = 0; nt < 4; ++nt)
            #pragma unroll
            for (int j = 0; j < 8; ++j)
                b2[nt][j] = (short)f2bf(W2[n1 * 16384 +
                                           (m2b * 32 + q * 8 + j) * 64 +
                                           nt * 16 + lr]);
        #pragma unroll
        for (int bl = 0; bl < 4; ++bl)
            #pragma unroll
            for (int nt = 0; nt < 4; ++nt)
                acc2[bl][nt] = MFMA16(a2[bl], b2[nt], acc2[bl][nt]);
    }

    #pragma unroll
    for (int bl = 0; bl < 4; ++bl)
        #pragma unroll
        for (int nt = 0; nt < 4; ++nt)
            #pragma unroll
            for (int g = 0; g < 4; ++g) {
                long row = bt * 64 + bl * 16 + q * 4 + g;
                long col = (long)n1 * 64 + nt * 16 + lr;
                out[row * 4096 + col] = acc2[bl][nt][g];
            }
}

extern "C" void kernel_launch(void* const* d_in, const int* in_sizes, int n_in,
                              void* d_out, int out_size, void* d_ws, size_t ws_size,
                              hipStream_t stream) {
    const float* x  = (const float*)d_in[0];   // (4096, 4096) fp32
    const float* W1 = (const float*)d_in[1];   // (64, 64, 256) fp32
    const float* W2 = (const float*)d_in[2];   // (64, 256, 64) fp32
    float* out = (float*)d_out;

    const size_t N_W1F = (size_t)64 * 16384;          // 2 MiB
    const size_t N_W2F = (size_t)64 * 16384;          // 2 MiB
    const size_t N_XF  = (size_t)4096 * 4096;         // 32 MiB
    const size_t WS_NEED = (N_W1F + N_W2F + N_XF) * sizeof(u16);  // 36 MiB

    if (ws_size >= WS_NEED) {
        u16* W1F = (u16*)d_ws;
        u16* W2F = W1F + N_W1F;
        u16* XF  = W2F + N_W2F;
        prep_all<<<4096 + 64 + 64, 256, 0, stream>>>(x, W1, W2, W1F, W2F, XF);
        btt_db<<<512, 512, 0, stream>>>(XF, W1F, W2F, out);
    } else {
        btt_nows<<<512, 512, 0, stream>>>(x, W1, W2, out);
    }
}